// Round 1
// baseline (15645.692 us; speedup 1.0000x reference)
//
#include <hip/hip_runtime.h>

typedef _Float16 half8 __attribute__((ext_vector_type(8)));
typedef _Float16 half4 __attribute__((ext_vector_type(4)));
typedef float f32x16 __attribute__((ext_vector_type(16)));

#define SEQ 512
#define HID 1024
#define HB 65536  // 64*1024 elements per h buffer / per x time-slice

// ---- LDS layout (bytes) ----
#define LDS_WIH 0
#define LDS_WHH 65536
#define LDS_GX 131072  // [64][33] f32
#define LDS_GH 139520
#define LDS_C 147968   // [64][8] f32
#define LDS_BIAS 150016
#define LDS_TOTAL 150144

__device__ __forceinline__ float sigf(float x) { return 1.0f / (1.0f + __expf(-x)); }
__device__ __forceinline__ float tanhfast(float x) {
  x = fminf(fmaxf(x, -44.0f), 44.0f);
  float e = __expf(2.0f * x);
  return (e - 1.0f) / (e + 1.0f);
}

__global__ __launch_bounds__(256, 1) void cvt_f32_f16(const float* __restrict__ in,
                                                      _Float16* __restrict__ out, int n4) {
  int stride = gridDim.x * blockDim.x;
  for (int i = blockIdx.x * blockDim.x + threadIdx.x; i < n4; i += stride) {
    float4 v = ((const float4*)in)[i];
    half4 o;
    o[0] = (_Float16)v.x; o[1] = (_Float16)v.y; o[2] = (_Float16)v.z; o[3] = (_Float16)v.w;
    ((half4*)out)[i] = o;
  }
}

// Persistent fused 2-layer LSTM. 256 WGs: blocks 0..127 = layer0, 128..255 = layer1.
// WG w owns 8 h-columns j0=8*(w&127) of its layer: gate rows {i,f,g,o}x8 = 32 rows
// of W_ih and W_hh, staged fp16 in LDS (XOR-swizzled). Wavefront schedule:
// global step s: layer0 computes t=s (s<512), layer1 computes t=s-1 (s>=1).
// Layer1's input is layer0's h ping-pong buffer directly.
__global__ __launch_bounds__(256, 1) void lstm_fused(
    const _Float16* __restrict__ xh,
    const float* __restrict__ Wih0, const float* __restrict__ Whh0, const float* __restrict__ b0,
    const float* __restrict__ Wih1, const float* __restrict__ Whh1, const float* __restrict__ b1,
    _Float16* __restrict__ h0buf, _Float16* __restrict__ h1buf,
    int* __restrict__ bar, float* __restrict__ out) {
  extern __shared__ char smem[];
  float* gX = (float*)(smem + LDS_GX);
  float* gH = (float*)(smem + LDS_GH);
  float* cst = (float*)(smem + LDS_C);
  float* bls = (float*)(smem + LDS_BIAS);

  const int tid = threadIdx.x;
  const int lane = tid & 63;
  const int wave = tid >> 6;
  const int mtile = wave & 1;   // which 32 batches
  const int gsel = wave >> 1;   // 0 = input GEMM, 1 = recurrent GEMM
  const int wg = blockIdx.x;
  const int layer = wg >> 7;
  const int j0 = (wg & 127) * 8;

  // ---- prologue: stage W slices (fp32 global -> fp16 LDS, swizzled) ----
  const float* wsrc0 = layer ? Wih1 : Wih0;
  const float* wsrc1 = layer ? Whh1 : Whh0;
  for (int m = 0; m < 2; ++m) {
    const float* src = m ? wsrc1 : wsrc0;
    char* base = smem + (m ? LDS_WHH : LDS_WIH);
    for (int q = tid; q < 4096; q += 256) {
      int r = q >> 7;               // local gate row 0..31
      int kc = (q & 127) << 3;      // k chunk base (elements)
      int grow = ((r >> 3) << 10) + j0 + (r & 7);  // global gate row
      const float* sp = src + (size_t)grow * 1024 + kc;
      half8 v;
#pragma unroll
      for (int j = 0; j < 8; ++j) v[j] = (_Float16)sp[j];
      *(half8*)(base + r * 2048 + ((kc * 2) ^ ((r & 7) << 4))) = v;
    }
  }
  const float* bsrc = layer ? b1 : b0;
  if (tid < 32) {
    int grow = ((tid >> 3) << 10) + j0 + (tid & 7);
    bls[tid] = bsrc[grow];
  }
  for (int q = tid; q < 512; q += 256) cst[q] = 0.0f;
  __syncthreads();

  // per-wave constant addressing
  const int arow = mtile * 32 + (lane & 31);   // batch row for A fragment
  const int asub = (lane >> 5) << 3;           // k sub-offset (elements)
  const int brow = lane & 31;                  // gate row for B fragment
  const int bswz = (brow & 7) << 4;
  const int bsub = (lane >> 5) << 4;           // k sub-offset (bytes)
  const char* wBase = smem + (gsel ? LDS_WHH : LDS_WIH) + brow * 2048;
  _Float16* hSelf = layer ? h1buf : h0buf;
  float* outy = out;
  float* outh = out + 33554432;
  float* outc = out + 33685504;

  for (int s = 0; s <= SEQ; ++s) {
    const bool act = layer ? (s >= 1) : (s < SEQ);
    if (act) {
      const int t = layer ? s - 1 : s;
      const _Float16* hRead = hSelf + (size_t)(s & 1) * HB;
      const _Float16* aBase =
          gsel ? hRead
               : (layer ? (h0buf + (size_t)(s & 1) * HB) : (xh + (size_t)t * HB));
      const _Float16* aPtr = aBase + arow * HID + asub;

      f32x16 acc[4];
#pragma unroll
      for (int q = 0; q < 4; ++q) {
#pragma unroll
        for (int i = 0; i < 16; ++i) acc[q][i] = 0.0f;
      }

      // K = 1024 = 64 ksteps of 16; manual 2-window prefetch (all indices static)
      half8 aw[2][8];
      half8 bw[2][8];
#pragma unroll
      for (int u = 0; u < 8; ++u) {
        aw[0][u] = *(const half8*)(aPtr + u * 16);
        bw[0][u] = *(const half8*)(wBase + ((u * 32 + bsub) ^ bswz));
      }
#pragma unroll
      for (int w = 0; w < 8; ++w) {
        const int cur = w & 1, nxt = cur ^ 1;
        if (w < 7) {
#pragma unroll
          for (int u = 0; u < 8; ++u) {
            int kk = (w + 1) * 8 + u;
            aw[nxt][u] = *(const half8*)(aPtr + kk * 16);
            bw[nxt][u] = *(const half8*)(wBase + ((kk * 32 + bsub) ^ bswz));
          }
        }
#pragma unroll
        for (int u = 0; u < 8; ++u) {
          acc[u & 3] = __builtin_amdgcn_mfma_f32_32x32x16_f16(aw[cur][u], bw[cur][u],
                                                              acc[u & 3], 0, 0, 0);
        }
      }
      f32x16 tot = acc[0] + acc[1] + acc[2] + acc[3];

      // write partial gates to LDS: D layout row=(r&3)+8*(r>>2)+4*(lane>>5), col=lane&31
      float* gbuf = gsel ? gH : gX;
#pragma unroll
      for (int r = 0; r < 16; ++r) {
        int bl = (r & 3) + ((r >> 2) << 3) + ((lane >> 5) << 2);
        gbuf[(mtile * 32 + bl) * 33 + brow] = tot[r];
      }
      __syncthreads();

      _Float16* hw = hSelf + (size_t)((s + 1) & 1) * HB;
      const bool last = (s == (layer ? SEQ : SEQ - 1));
#pragma unroll
      for (int it = 0; it < 2; ++it) {
        int item = tid + it * 256;
        int b = item >> 3, j = item & 7;
        float vi = gX[b * 33 + j] + gH[b * 33 + j] + bls[j];
        float vf = gX[b * 33 + 8 + j] + gH[b * 33 + 8 + j] + bls[8 + j];
        float vg = gX[b * 33 + 16 + j] + gH[b * 33 + 16 + j] + bls[16 + j];
        float vo = gX[b * 33 + 24 + j] + gH[b * 33 + 24 + j] + bls[24 + j];
        float i_ = sigf(vi), f_ = sigf(vf), g_ = tanhfast(vg), o_ = sigf(vo);
        float cp = cst[item];
        float hn = o_ * tanhfast(cp);  // faithful: h uses PREVIOUS cell state
        float cn = f_ * cp + i_ * g_;
        cst[item] = cn;
        int col = j0 + j;
        hw[b * HID + col] = (_Float16)hn;
        if (layer) outy[(size_t)t * HB + b * HID + col] = hn;
        if (last) {
          outh[layer * HB + b * HID + col] = hn;
          outc[layer * HB + b * HID + col] = cn;
        }
      }
    }
    // ---- grid barrier (monotonic counter, agent-scope fences) ----
    __syncthreads();
    if (tid == 0) {
      __threadfence();
      atomicAdd(bar, 1);
      const int target = 256 * (s + 1);
      while (__hip_atomic_load(bar, __ATOMIC_RELAXED, __HIP_MEMORY_SCOPE_AGENT) < target)
        __builtin_amdgcn_s_sleep(2);
      __threadfence();
    }
    __syncthreads();
  }
}

extern "C" void kernel_launch(void* const* d_in, const int* in_sizes, int n_in,
                              void* d_out, int out_size, void* d_ws, size_t ws_size,
                              hipStream_t stream) {
  const float* x = (const float*)d_in[0];
  const float* Wih0 = (const float*)d_in[1];
  const float* Whh0 = (const float*)d_in[2];
  const float* b0 = (const float*)d_in[3];
  const float* Wih1 = (const float*)d_in[4];
  const float* Whh1 = (const float*)d_in[5];
  const float* b1 = (const float*)d_in[6];
  float* out = (float*)d_out;

  char* ws = (char*)d_ws;
  _Float16* xh = (_Float16*)ws;                          // 512*64*1024 f16 = 67108864 B
  _Float16* h0 = (_Float16*)(ws + 67108864);             // 2 * 65536 f16
  _Float16* h1 = (_Float16*)(ws + 67108864 + 262144);    // 2 * 65536 f16
  int* bar = (int*)(ws + 67108864 + 524288);

  hipMemsetAsync(ws + 67108864, 0, 524288 + 256, stream);
  cvt_f32_f16<<<2048, 256, 0, stream>>>(x, xh, 33554432 / 4);
  lstm_fused<<<256, 256, LDS_TOTAL, stream>>>(xh, Wih0, Whh0, b0, Wih1, Whh1, b1,
                                              h0, h1, bar, out);
}

// Round 2
// 11935.049 us; speedup vs baseline: 1.3109x; 1.3109x over previous
//
#include <hip/hip_runtime.h>

typedef _Float16 half8 __attribute__((ext_vector_type(8)));
typedef _Float16 half4 __attribute__((ext_vector_type(4)));
typedef float f32x16 __attribute__((ext_vector_type(16)));
typedef unsigned long long u64;

#define SEQ 512
#define HID 1024
#define HB 65536  // 64*1024 elements per h buffer / per x time-slice

// ---- LDS layout (bytes) ----
#define LDS_WIH 0
#define LDS_WHH 65536
#define LDS_GX 131072  // [64][33] f32
#define LDS_GH 139520
#define LDS_C 147968   // [64][8] f32
#define LDS_BIAS 150016
#define LDS_TOTAL 150144

__device__ __forceinline__ float sigf(float x) { return 1.0f / (1.0f + __expf(-x)); }
__device__ __forceinline__ float tanhfast(float x) {
  x = fminf(fmaxf(x, -44.0f), 44.0f);
  float e = __expf(2.0f * x);
  return (e - 1.0f) / (e + 1.0f);
}

__global__ __launch_bounds__(256, 1) void cvt_f32_f16(const float* __restrict__ in,
                                                      _Float16* __restrict__ out, int n4) {
  int stride = gridDim.x * blockDim.x;
  for (int i = blockIdx.x * blockDim.x + threadIdx.x; i < n4; i += stride) {
    float4 v = ((const float4*)in)[i];
    half4 o;
    o[0] = (_Float16)v.x; o[1] = (_Float16)v.y; o[2] = (_Float16)v.z; o[3] = (_Float16)v.w;
    ((half4*)out)[i] = o;
  }
}

// A-fragment load: COH = device-coherent (bypass L1/L2, always fresh) for h buffers;
// plain cached for xh (written by a prior kernel, read-only).
template <bool COH>
__device__ __forceinline__ half8 ldA(const _Float16* p) {
  if constexpr (COH) {
    union { half8 v; u64 q[2]; } r;
    r.q[0] = __hip_atomic_load((const u64*)p, __ATOMIC_RELAXED, __HIP_MEMORY_SCOPE_AGENT);
    r.q[1] = __hip_atomic_load(((const u64*)p) + 1, __ATOMIC_RELAXED, __HIP_MEMORY_SCOPE_AGENT);
    return r.v;
  } else {
    return *(const half8*)p;
  }
}

// One wave's [32 batch] x [32 gate] x K=1024 GEMM. 8 windows of 8 ksteps;
// A prefetched 3 windows ahead (hides ~600cy coherence-point latency),
// B (LDS, swizzled) 1 window ahead. All indices compile-time.
template <bool COH>
__device__ __forceinline__ f32x16 gemm_k(const _Float16* aPtr, const char* wB,
                                         int bsub, int bswz) {
  f32x16 acc[4];
#pragma unroll
  for (int q = 0; q < 4; ++q)
#pragma unroll
    for (int i = 0; i < 16; ++i) acc[q][i] = 0.0f;

  half8 aw[4][8];
  half8 bw[2][8];
#pragma unroll
  for (int w0 = 0; w0 < 3; ++w0)
#pragma unroll
    for (int u = 0; u < 8; ++u) aw[w0][u] = ldA<COH>(aPtr + (w0 * 8 + u) * 16);
#pragma unroll
  for (int u = 0; u < 8; ++u)
    bw[0][u] = *(const half8*)(wB + ((u * 32 + bsub) ^ bswz));

#pragma unroll
  for (int w = 0; w < 8; ++w) {
    if (w + 3 < 8) {
#pragma unroll
      for (int u = 0; u < 8; ++u)
        aw[(w + 3) & 3][u] = ldA<COH>(aPtr + ((w + 3) * 8 + u) * 16);
    }
    if (w + 1 < 8) {
#pragma unroll
      for (int u = 0; u < 8; ++u)
        bw[(w + 1) & 1][u] = *(const half8*)(wB + ((((w + 1) * 8 + u) * 32 + bsub) ^ bswz));
    }
#pragma unroll
    for (int u = 0; u < 8; ++u)
      acc[u & 3] = __builtin_amdgcn_mfma_f32_32x32x16_f16(aw[w & 3][u], bw[w & 1][u],
                                                          acc[u & 3], 0, 0, 0);
  }
  return acc[0] + acc[1] + acc[2] + acc[3];
}

// Persistent fused 2-layer LSTM. 256 WGs: 0..127 layer0, 128..255 layer1.
// Wavefront schedule: step s: layer0 does t=s, layer1 does t=s-1.
// Grid sync: distributed flag barrier, all traffic device-coherent (sc0 sc1),
// zero fences, zero RMW atomics.
__global__ __launch_bounds__(256, 1) void lstm_fused(
    const _Float16* __restrict__ xh,
    const float* __restrict__ Wih0, const float* __restrict__ Whh0, const float* __restrict__ b0,
    const float* __restrict__ Wih1, const float* __restrict__ Whh1, const float* __restrict__ b1,
    _Float16* __restrict__ h0buf, _Float16* __restrict__ h1buf,
    unsigned* __restrict__ flags, float* __restrict__ out) {
  extern __shared__ char smem[];
  float* gX = (float*)(smem + LDS_GX);
  float* gH = (float*)(smem + LDS_GH);
  float* cst = (float*)(smem + LDS_C);
  float* bls = (float*)(smem + LDS_BIAS);

  const int tid = threadIdx.x;
  const int lane = tid & 63;
  const int wave = tid >> 6;
  const int mtile = wave & 1;   // which 32 batches
  const int gsel = wave >> 1;   // 0 = input GEMM, 1 = recurrent GEMM
  const int wg = blockIdx.x;
  const int layer = wg >> 7;
  const int j0 = (wg & 127) * 8;

  // ---- prologue: stage W slices (fp32 global -> fp16 LDS, swizzled) ----
  const float* wsrc0 = layer ? Wih1 : Wih0;
  const float* wsrc1 = layer ? Whh1 : Whh0;
  for (int m = 0; m < 2; ++m) {
    const float* src = m ? wsrc1 : wsrc0;
    char* base = smem + (m ? LDS_WHH : LDS_WIH);
    for (int q = tid; q < 4096; q += 256) {
      int r = q >> 7;               // local gate row 0..31
      int kc = (q & 127) << 3;      // k chunk base (elements)
      int grow = ((r >> 3) << 10) + j0 + (r & 7);  // global gate row
      const float* sp = src + (size_t)grow * 1024 + kc;
      half8 v;
#pragma unroll
      for (int j = 0; j < 8; ++j) v[j] = (_Float16)sp[j];
      *(half8*)(base + r * 2048 + ((kc * 2) ^ ((r & 7) << 4))) = v;
    }
  }
  const float* bsrc = layer ? b1 : b0;
  if (tid < 32) {
    int grow = ((tid >> 3) << 10) + j0 + (tid & 7);
    bls[tid] = bsrc[grow];
  }
  for (int q = tid; q < 512; q += 256) cst[q] = 0.0f;
  __syncthreads();

  // per-wave constant addressing
  const int arow = mtile * 32 + (lane & 31);   // batch row for A fragment
  const int asub = (lane >> 5) << 3;           // k sub-offset (elements)
  const int brow = lane & 31;                  // gate row for B fragment
  const int bswz = (brow & 7) << 4;
  const int bsub = (lane >> 5) << 4;           // k sub-offset (bytes)
  const char* wBase = smem + (gsel ? LDS_WHH : LDS_WIH) + brow * 2048;
  _Float16* hSelf = layer ? h1buf : h0buf;
  float* outy = out;
  float* outh = out + 33554432;
  float* outc = out + 33685504;

  for (int s = 0; s <= SEQ; ++s) {
    const bool act = layer ? (s >= 1) : (s < SEQ);
    if (act) {
      const int t = layer ? s - 1 : s;
      const _Float16* aBase =
          gsel ? (hSelf + (size_t)(s & 1) * HB)
               : (layer ? (h0buf + (size_t)(s & 1) * HB) : (xh + (size_t)t * HB));
      const _Float16* aPtr = aBase + arow * HID + asub;

      f32x16 tot;
      if (layer == 0 && gsel == 0)
        tot = gemm_k<false>(aPtr, wBase, bsub, bswz);  // xh: plain cached
      else
        tot = gemm_k<true>(aPtr, wBase, bsub, bswz);   // h: device-coherent

      // partial gates -> LDS: D layout row=(r&3)+8*(r>>2)+4*(lane>>5), col=lane&31
      float* gbuf = gsel ? gH : gX;
#pragma unroll
      for (int r = 0; r < 16; ++r) {
        int bl = (r & 3) + ((r >> 2) << 3) + ((lane >> 5) << 2);
        gbuf[(mtile * 32 + bl) * 33 + brow] = tot[r];
      }
      __syncthreads();

      unsigned* hwU = (unsigned*)(hSelf + (size_t)((s + 1) & 1) * HB);
      const bool last = (s == (layer ? SEQ : SEQ - 1));
#pragma unroll
      for (int it = 0; it < 2; ++it) {
        int item = tid + it * 256;
        int b = item >> 3, j = item & 7;
        float vi = gX[b * 33 + j] + gH[b * 33 + j] + bls[j];
        float vf = gX[b * 33 + 8 + j] + gH[b * 33 + 8 + j] + bls[8 + j];
        float vg = gX[b * 33 + 16 + j] + gH[b * 33 + 16 + j] + bls[16 + j];
        float vo = gX[b * 33 + 24 + j] + gH[b * 33 + 24 + j] + bls[24 + j];
        float i_ = sigf(vi), f_ = sigf(vf), g_ = tanhfast(vg), o_ = sigf(vo);
        float cp = cst[item];
        float hn = o_ * tanhfast(cp);  // faithful: h uses PREVIOUS cell state
        float cn = f_ * cp + i_ * g_;
        cst[item] = cn;
        int col = j0 + j;
        // coherent packed store of h (2 cols per uint), paired via shfl
        union { _Float16 h; unsigned short u; } hb; hb.h = (_Float16)hn;
        int pr = __shfl_xor((int)hb.u, 1, 64);
        if (!(j & 1)) {
          unsigned pk = (unsigned)hb.u | ((unsigned)(unsigned short)pr << 16);
          __hip_atomic_store(hwU + b * 512 + ((col) >> 1), pk, __ATOMIC_RELAXED,
                             __HIP_MEMORY_SCOPE_AGENT);
        }
        if (layer) outy[(size_t)t * HB + b * HID + col] = hn;
        if (last) {
          outh[layer * HB + b * HID + col] = hn;
          outc[layer * HB + b * HID + col] = cn;
        }
      }
    }
    if (s == SEQ) break;
    // ---- distributed flag barrier ----
    // __syncthreads drains vmcnt(0) per wave: all sc1 h-stores are ack'd at the
    // coherence point before any thread proceeds -> flag store is a release.
    __syncthreads();
    if (tid == 0)
      __hip_atomic_store(&flags[wg], (unsigned)(s + 1), __ATOMIC_RELAXED,
                         __HIP_MEMORY_SCOPE_AGENT);
    if (tid < 64) {
      const u64* f64 = (const u64*)flags;
      const unsigned target = (unsigned)(s + 1);
      bool ok;
      do {
        u64 a = __hip_atomic_load(f64 + tid, __ATOMIC_RELAXED, __HIP_MEMORY_SCOPE_AGENT);
        u64 b = __hip_atomic_load(f64 + 64 + tid, __ATOMIC_RELAXED, __HIP_MEMORY_SCOPE_AGENT);
        unsigned t1 = (unsigned)a, t2 = (unsigned)(a >> 32);
        unsigned t3 = (unsigned)b, t4 = (unsigned)(b >> 32);
        unsigned mn = t1 < t2 ? t1 : t2;
        unsigned mn2 = t3 < t4 ? t3 : t4;
        mn = mn < mn2 ? mn : mn2;
        ok = __all(mn >= target);
        if (!ok) __builtin_amdgcn_s_sleep(1);
      } while (!ok);
    }
    __syncthreads();
  }
}

extern "C" void kernel_launch(void* const* d_in, const int* in_sizes, int n_in,
                              void* d_out, int out_size, void* d_ws, size_t ws_size,
                              hipStream_t stream) {
  const float* x = (const float*)d_in[0];
  const float* Wih0 = (const float*)d_in[1];
  const float* Whh0 = (const float*)d_in[2];
  const float* b0 = (const float*)d_in[3];
  const float* Wih1 = (const float*)d_in[4];
  const float* Whh1 = (const float*)d_in[5];
  const float* b1 = (const float*)d_in[6];
  float* out = (float*)d_out;

  char* ws = (char*)d_ws;
  _Float16* xh = (_Float16*)ws;                          // 512*64*1024 f16 = 67108864 B
  _Float16* h0 = (_Float16*)(ws + 67108864);             // 2 * 65536 f16
  _Float16* h1 = (_Float16*)(ws + 67108864 + 262144);    // 2 * 65536 f16
  unsigned* flags = (unsigned*)(ws + 67108864 + 524288); // 256 u32

  // reset h ping-pong + flags every call (graph replays include this memset)
  hipMemsetAsync(ws + 67108864, 0, 524288 + 1024, stream);
  cvt_f32_f16<<<2048, 256, 0, stream>>>(x, xh, 33554432 / 4);
  lstm_fused<<<256, 256, LDS_TOTAL, stream>>>(xh, Wih0, Whh0, b0, Wih1, Whh1, b1,
                                              h0, h1, flags, out);
}

// Round 3
// 6253.810 us; speedup vs baseline: 2.5018x; 1.9084x over previous
//
#include <hip/hip_runtime.h>

typedef _Float16 half8 __attribute__((ext_vector_type(8)));
typedef _Float16 half4 __attribute__((ext_vector_type(4)));
typedef float f32x16 __attribute__((ext_vector_type(16)));
typedef unsigned long long u64;

#define SEQ 512
#define HID 1024
#define HB 65536  // 64*1024 elements per h slice / per x time-slice

// ---- LDS layout (bytes) ----
#define LDS_WIH 0
#define LDS_WHH 65536
#define LDS_GX 131072  // [64][33] f32
#define LDS_GH 139520
#define LDS_C 147968   // [64][8] f32
#define LDS_BIAS 150016
#define LDS_TOTAL 150144

__device__ __forceinline__ float sigf(float x) { return 1.0f / (1.0f + __expf(-x)); }
__device__ __forceinline__ float tanhfast(float x) {
  x = fminf(fmaxf(x, -44.0f), 44.0f);
  float e = __expf(2.0f * x);
  return (e - 1.0f) / (e + 1.0f);
}

__global__ __launch_bounds__(256, 1) void cvt_f32_f16(const float* __restrict__ in,
                                                      _Float16* __restrict__ out, int n4) {
  int stride = gridDim.x * blockDim.x;
  for (int i = blockIdx.x * blockDim.x + threadIdx.x; i < n4; i += stride) {
    float4 v = ((const float4*)in)[i];
    half4 o;
    o[0] = (_Float16)v.x; o[1] = (_Float16)v.y; o[2] = (_Float16)v.z; o[3] = (_Float16)v.w;
    ((half4*)out)[i] = o;
  }
}

// One wave's [32 batch] x [32 gate] x K=1024 GEMM. A via plain cached loads
// (h history slices are write-once -> L2-cacheable, broadcast amplified by L2).
// B from LDS (fp16, XOR-swizzled). 8 windows of 8 ksteps; A prefetched 3 windows
// ahead (hides first-per-XCD L3 miss ~600cy), B 1 window. All indices static.
__device__ __forceinline__ f32x16 gemm_k(const _Float16* aPtr, const char* wB,
                                         int bsub, int bswz) {
  f32x16 acc[4];
#pragma unroll
  for (int q = 0; q < 4; ++q)
#pragma unroll
    for (int i = 0; i < 16; ++i) acc[q][i] = 0.0f;

  half8 aw[4][8];
  half8 bw[2][8];
#pragma unroll
  for (int w0 = 0; w0 < 3; ++w0)
#pragma unroll
    for (int u = 0; u < 8; ++u) aw[w0][u] = *(const half8*)(aPtr + (w0 * 8 + u) * 16);
#pragma unroll
  for (int u = 0; u < 8; ++u)
    bw[0][u] = *(const half8*)(wB + ((u * 32 + bsub) ^ bswz));

#pragma unroll
  for (int w = 0; w < 8; ++w) {
    if (w + 3 < 8) {
#pragma unroll
      for (int u = 0; u < 8; ++u)
        aw[(w + 3) & 3][u] = *(const half8*)(aPtr + ((w + 3) * 8 + u) * 16);
    }
    if (w + 1 < 8) {
#pragma unroll
      for (int u = 0; u < 8; ++u)
        bw[(w + 1) & 1][u] = *(const half8*)(wB + ((((w + 1) * 8 + u) * 32 + bsub) ^ bswz));
    }
#pragma unroll
    for (int u = 0; u < 8; ++u)
      acc[u & 3] = __builtin_amdgcn_mfma_f32_32x32x16_f16(aw[w & 3][u], bw[w & 1][u],
                                                          acc[u & 3], 0, 0, 0);
  }
  return acc[0] + acc[1] + acc[2] + acc[3];
}

// Persistent fused 2-layer LSTM. 256 WGs: 0..127 layer0, 128..255 layer1.
// Wavefront schedule: iter s: layer0 does t=s, layer1 does t=s-1.
// h state: full per-step history (write-once addresses). Writers release via
// sc1 write-through + vmcnt drain at __syncthreads; readers use plain cached
// loads (L2 broadcast). Split flag barrier: layer0 waits only on layer0.
__global__ __launch_bounds__(256, 1) void lstm_fused(
    const _Float16* __restrict__ xh,
    const float* __restrict__ Wih0, const float* __restrict__ Whh0, const float* __restrict__ b0,
    const float* __restrict__ Wih1, const float* __restrict__ Whh1, const float* __restrict__ b1,
    _Float16* __restrict__ h0buf, _Float16* __restrict__ h1buf,
    unsigned* __restrict__ flags, float* __restrict__ out) {
  extern __shared__ char smem[];
  float* gX = (float*)(smem + LDS_GX);
  float* gH = (float*)(smem + LDS_GH);
  float* cst = (float*)(smem + LDS_C);
  float* bls = (float*)(smem + LDS_BIAS);

  const int tid = threadIdx.x;
  const int lane = tid & 63;
  const int wave = tid >> 6;
  const int mtile = wave & 1;   // which 32 batches
  const int gsel = wave >> 1;   // 0 = input GEMM, 1 = recurrent GEMM
  const int wg = blockIdx.x;
  const int layer = wg >> 7;
  const int j0 = (wg & 127) * 8;

  // ---- prologue: stage W slices (fp32 global -> fp16 LDS, swizzled) ----
  const float* wsrc0 = layer ? Wih1 : Wih0;
  const float* wsrc1 = layer ? Whh1 : Whh0;
  for (int m = 0; m < 2; ++m) {
    const float* src = m ? wsrc1 : wsrc0;
    char* base = smem + (m ? LDS_WHH : LDS_WIH);
    for (int q = tid; q < 4096; q += 256) {
      int r = q >> 7;               // local gate row 0..31
      int kc = (q & 127) << 3;      // k chunk base (elements)
      int grow = ((r >> 3) << 10) + j0 + (r & 7);  // global gate row
      const float* sp = src + (size_t)grow * 1024 + kc;
      half8 v;
#pragma unroll
      for (int j = 0; j < 8; ++j) v[j] = (_Float16)sp[j];
      *(half8*)(base + r * 2048 + ((kc * 2) ^ ((r & 7) << 4))) = v;
    }
  }
  const float* bsrc = layer ? b1 : b0;
  if (tid < 32) {
    int grow = ((tid >> 3) << 10) + j0 + (tid & 7);
    bls[tid] = bsrc[grow];
  }
  for (int q = tid; q < 512; q += 256) cst[q] = 0.0f;
  __syncthreads();

  // per-wave constant addressing
  const int arow = mtile * 32 + (lane & 31);   // batch row for A fragment
  const int asub = (lane >> 5) << 3;           // k sub-offset (elements)
  const int brow = lane & 31;                  // gate row for B fragment
  const int bswz = (brow & 7) << 4;
  const int bsub = (lane >> 5) << 4;           // k sub-offset (bytes)
  const char* wBase = smem + (gsel ? LDS_WHH : LDS_WIH) + brow * 2048;
  _Float16* hSelf = layer ? h1buf : h0buf;
  float* outy = out;
  float* outh = out + 33554432;
  float* outc = out + 33685504;

  for (int s = 0; s <= SEQ; ++s) {
    const bool act = layer ? (s >= 1) : (s < SEQ);
    if (act) {
      const int t = layer ? s - 1 : s;
      const int rs = layer ? s - 1 : s;  // own-layer steps completed
      const _Float16* aBase =
          gsel ? (hSelf + (size_t)rs * HB)
               : (layer ? (h0buf + (size_t)s * HB) : (xh + (size_t)t * HB));
      const _Float16* aPtr = aBase + arow * HID + asub;

      f32x16 tot = gemm_k(aPtr, wBase, bsub, bswz);

      // partial gates -> LDS: D layout row=(r&3)+8*(r>>2)+4*(lane>>5), col=lane&31
      float* gbuf = gsel ? gH : gX;
#pragma unroll
      for (int r = 0; r < 16; ++r) {
        int bl = (r & 3) + ((r >> 2) << 3) + ((lane >> 5) << 2);
        gbuf[(mtile * 32 + bl) * 33 + brow] = tot[r];
      }
      __syncthreads();

      unsigned* hwU = (unsigned*)(hSelf + (size_t)(rs + 1) * HB);
      const bool last = (s == (layer ? SEQ : SEQ - 1));
#pragma unroll
      for (int it = 0; it < 2; ++it) {
        int item = tid + it * 256;
        int b = item >> 3, j = item & 7;
        float vi = gX[b * 33 + j] + gH[b * 33 + j] + bls[j];
        float vf = gX[b * 33 + 8 + j] + gH[b * 33 + 8 + j] + bls[8 + j];
        float vg = gX[b * 33 + 16 + j] + gH[b * 33 + 16 + j] + bls[16 + j];
        float vo = gX[b * 33 + 24 + j] + gH[b * 33 + 24 + j] + bls[24 + j];
        float i_ = sigf(vi), f_ = sigf(vf), g_ = tanhfast(vg), o_ = sigf(vo);
        float cp = cst[item];
        float hn = o_ * tanhfast(cp);  // faithful: h uses PREVIOUS cell state
        float cn = f_ * cp + i_ * g_;
        cst[item] = cn;
        int col = j0 + j;
        // h store: write-through to coherence point (release via vmcnt drain at
        // the next __syncthreads + flag store). Packed 2 cols per u32.
        union { _Float16 h; unsigned short u; } hb; hb.h = (_Float16)hn;
        int pr = __shfl_xor((int)hb.u, 1, 64);
        if (!(j & 1)) {
          unsigned pk = (unsigned)hb.u | ((unsigned)(unsigned short)pr << 16);
          __hip_atomic_store(hwU + b * 512 + (col >> 1), pk, __ATOMIC_RELAXED,
                             __HIP_MEMORY_SCOPE_AGENT);
        }
        if (layer) outy[(size_t)t * HB + b * HID + col] = hn;
        if (last) {
          outh[layer * HB + b * HID + col] = hn;
          outc[layer * HB + b * HID + col] = cn;
        }
      }
    }
    if (s == SEQ) break;
    // ---- split distributed flag barrier ----
    // __syncthreads drains vmcnt(0) per wave: all sc1 h-stores ack'd at the
    // coherence point before the flag store -> flag store is a release.
    __syncthreads();
    if (tid == 0)
      __hip_atomic_store(&flags[wg], (unsigned)(s + 1), __ATOMIC_RELAXED,
                         __HIP_MEMORY_SCOPE_AGENT);
    if (tid < 64) {
      const u64* f64 = (const u64*)flags;
      const unsigned target = (unsigned)(s + 1);
      bool ok;
      do {
        // layer0 waits only on layer0 peers (flags[0..127]); layer1 on all 256.
        u64 a = __hip_atomic_load(f64 + tid, __ATOMIC_RELAXED, __HIP_MEMORY_SCOPE_AGENT);
        unsigned t1 = (unsigned)a, t2 = (unsigned)(a >> 32);
        unsigned mn = t1 < t2 ? t1 : t2;
        if (layer) {
          u64 b = __hip_atomic_load(f64 + 64 + tid, __ATOMIC_RELAXED,
                                    __HIP_MEMORY_SCOPE_AGENT);
          unsigned t3 = (unsigned)b, t4 = (unsigned)(b >> 32);
          unsigned mn2 = t3 < t4 ? t3 : t4;
          mn = mn < mn2 ? mn : mn2;
        }
        ok = __all(mn >= target);
        if (!ok) __builtin_amdgcn_s_sleep(1);
      } while (!ok);
    }
    __syncthreads();
  }
}

extern "C" void kernel_launch(void* const* d_in, const int* in_sizes, int n_in,
                              void* d_out, int out_size, void* d_ws, size_t ws_size,
                              hipStream_t stream) {
  const float* x = (const float*)d_in[0];
  const float* Wih0 = (const float*)d_in[1];
  const float* Whh0 = (const float*)d_in[2];
  const float* b0 = (const float*)d_in[3];
  const float* Wih1 = (const float*)d_in[4];
  const float* Whh1 = (const float*)d_in[5];
  const float* b1 = (const float*)d_in[6];
  float* out = (float*)d_out;

  char* ws = (char*)d_ws;
  _Float16* xh = (_Float16*)ws;                       // 512*64*1024 f16 = 67,108,864 B
  _Float16* h0 = (_Float16*)(ws + 67108864);          // 513 slices x 131072 B
  _Float16* h1 = (_Float16*)(ws + 134348800);         // 513 slices x 131072 B
  unsigned* flags = (unsigned*)(ws + 201588736);      // 256 u32

  // zero only what each call needs: slice 0 of each h history + flags
  hipMemsetAsync(h0, 0, 131072, stream);
  hipMemsetAsync(h1, 0, 131072, stream);
  hipMemsetAsync(flags, 0, 1024, stream);
  cvt_f32_f16<<<2048, 256, 0, stream>>>(x, xh, 33554432 / 4);
  lstm_fused<<<256, 256, LDS_TOTAL, stream>>>(xh, Wih0, Whh0, b0, Wih1, Whh1, b1,
                                              h0, h1, flags, out);
}

// Round 4
// 5474.065 us; speedup vs baseline: 2.8581x; 1.1424x over previous
//
#include <hip/hip_runtime.h>

typedef _Float16 half8 __attribute__((ext_vector_type(8)));
typedef _Float16 half4 __attribute__((ext_vector_type(4)));
typedef float f32x16 __attribute__((ext_vector_type(16)));
typedef unsigned long long u64;

#define SEQ 512
#define HID 1024
#define HB 65536  // elements per h slice / per x time-slice

// ---- LDS layout (bytes) ----
#define WROW 2064  // 2048 B data + 16 B pad: 2064 mod 512 == 16 -> conflict-free b128
#define LDS_WIH 0
#define LDS_WHH 66048
#define LDS_GX 132096   // [64][36] f32 = 9216
#define LDS_GH 141312
#define LDS_C 150528    // [64][8] f32
#define LDS_BIAS 152576
#define LDS_ARR 152704  // arrive counter
#define LDS_TOTAL 152768

__device__ __forceinline__ float sigf(float x) { return 1.0f / (1.0f + __expf(-x)); }
__device__ __forceinline__ float tanhfast(float x) {
  x = fminf(fmaxf(x, -44.0f), 44.0f);
  float e = __expf(2.0f * x);
  return (e - 1.0f) / (e + 1.0f);
}

__global__ __launch_bounds__(256, 1) void cvt_f32_f16(const float* __restrict__ in,
                                                      _Float16* __restrict__ out, int n4) {
  int stride = gridDim.x * blockDim.x;
  for (int i = blockIdx.x * blockDim.x + threadIdx.x; i < n4; i += stride) {
    float4 v = ((const float4*)in)[i];
    half4 o;
    o[0] = (_Float16)v.x; o[1] = (_Float16)v.y; o[2] = (_Float16)v.z; o[3] = (_Float16)v.w;
    ((half4*)out)[i] = o;
  }
}

// One wave's [32 batch] x [32 gate] x K=1024 GEMM. A: plain cached loads
// (write-once h history -> L2-amplified broadcast). B: LDS fp16, row stride
// 2064 B (bank-conflict-free b128). 8 windows x 8 ksteps; A prefetch 3 windows.
__device__ __forceinline__ f32x16 gemm_k(const _Float16* aPtr, const char* wB, int bsub) {
  f32x16 acc[4];
#pragma unroll
  for (int q = 0; q < 4; ++q)
#pragma unroll
    for (int i = 0; i < 16; ++i) acc[q][i] = 0.0f;

  half8 aw[4][8];
  half8 bw[2][8];
#pragma unroll
  for (int w0 = 0; w0 < 3; ++w0)
#pragma unroll
    for (int u = 0; u < 8; ++u) aw[w0][u] = *(const half8*)(aPtr + (w0 * 8 + u) * 16);
#pragma unroll
  for (int u = 0; u < 8; ++u) bw[0][u] = *(const half8*)(wB + u * 32 + bsub);

#pragma unroll
  for (int w = 0; w < 8; ++w) {
    if (w + 3 < 8) {
#pragma unroll
      for (int u = 0; u < 8; ++u)
        aw[(w + 3) & 3][u] = *(const half8*)(aPtr + ((w + 3) * 8 + u) * 16);
    }
    if (w + 1 < 8) {
#pragma unroll
      for (int u = 0; u < 8; ++u)
        bw[(w + 1) & 1][u] = *(const half8*)(wB + ((w + 1) * 8 + u) * 32 + bsub);
    }
#pragma unroll
    for (int u = 0; u < 8; ++u)
      acc[u & 3] = __builtin_amdgcn_mfma_f32_32x32x16_f16(aw[w & 3][u], bw[w & 1][u],
                                                          acc[u & 3], 0, 0, 0);
  }
  return acc[0] + acc[1] + acc[2] + acc[3];
}

// Persistent fused 2-layer LSTM, hierarchical epoch barrier.
// WGs 0..127 layer0 (WG0 = leader0 -> E0), 128..255 layer1 (WG128 = leader1 -> E1).
// flags[w]: layer0 -> steps completed (s+1); layer1 -> s. Members poll one 8B
// epoch word on mirror line (wg&3). h history = write-once slices; writers sc1
// write-through + per-wave vmcnt drain before flag; readers plain cached loads.
__global__ __launch_bounds__(256, 1) void lstm_fused(
    const _Float16* __restrict__ xh,
    const float* __restrict__ Wih0, const float* __restrict__ Whh0, const float* __restrict__ b0,
    const float* __restrict__ Wih1, const float* __restrict__ Whh1, const float* __restrict__ b1,
    _Float16* __restrict__ h0buf, _Float16* __restrict__ h1buf,
    unsigned* __restrict__ flags, unsigned* __restrict__ epoch, float* __restrict__ out) {
  extern __shared__ char smem[];
  float* gX = (float*)(smem + LDS_GX);
  float* gH = (float*)(smem + LDS_GH);
  float* cst = (float*)(smem + LDS_C);
  float* bls = (float*)(smem + LDS_BIAS);
  unsigned* arrCnt = (unsigned*)(smem + LDS_ARR);

  const int tid = threadIdx.x;
  const int lane = tid & 63;
  const int wave = tid >> 6;
  const int mtile = wave & 1;   // which 32 batches
  const int gsel = wave >> 1;   // 0 = input GEMM, 1 = recurrent GEMM
  const int wg = blockIdx.x;
  const int layer = wg >> 7;
  const int j0 = (wg & 127) * 8;

  // ---- prologue: stage W slices (fp32 global -> fp16 LDS) ----
  const float* wsrc0 = layer ? Wih1 : Wih0;
  const float* wsrc1 = layer ? Whh1 : Whh0;
  for (int m = 0; m < 2; ++m) {
    const float* src = m ? wsrc1 : wsrc0;
    char* base = smem + (m ? LDS_WHH : LDS_WIH);
    for (int q = tid; q < 4096; q += 256) {
      int r = q >> 7;               // local gate row 0..31
      int kc = (q & 127) << 3;      // k chunk base (elements)
      int grow = ((r >> 3) << 10) + j0 + (r & 7);  // global gate row
      const float* sp = src + (size_t)grow * 1024 + kc;
      half8 v;
#pragma unroll
      for (int j = 0; j < 8; ++j) v[j] = (_Float16)sp[j];
      *(half8*)(base + r * WROW + kc * 2) = v;
    }
  }
  const float* bsrc = layer ? b1 : b0;
  if (tid < 32) {
    int grow = ((tid >> 3) << 10) + j0 + (tid & 7);
    bls[tid] = bsrc[grow];
  }
  for (int q = tid; q < 512; q += 256) cst[q] = 0.0f;
  if (tid == 0) *arrCnt = 0u;
  __syncthreads();

  // per-wave constant addressing
  const int arow = mtile * 32 + (lane & 31);   // batch row for A fragment
  const int asub = (lane >> 5) << 3;           // k sub-offset (elements)
  const int brow = lane & 31;                  // gate row for B fragment
  const int bsub = (lane >> 5) << 4;           // k sub-offset (bytes)
  const char* wBase = smem + (gsel ? LDS_WHH : LDS_WIH) + brow * WROW;
  _Float16* hSelf = layer ? h1buf : h0buf;
  float* outy = out;
  float* outh = out + 33554432;
  float* outc = out + 33685504;

  for (int s = 0; s <= SEQ; ++s) {
    const bool act = layer ? (s >= 1) : (s < SEQ);
    if (act) {
      const int t = layer ? s - 1 : s;
      const int rs = layer ? s - 1 : s;  // own-layer steps completed
      const _Float16* aBase =
          gsel ? (hSelf + (size_t)rs * HB)
               : (layer ? (h0buf + (size_t)s * HB) : (xh + (size_t)t * HB));
      const _Float16* aPtr = aBase + arow * HID + asub;

      f32x16 tot = gemm_k(aPtr, wBase, bsub);

      // partial gates -> LDS: D layout row=(r&3)+8*(r>>2)+4*(lane>>5), col=lane&31
      float* gbuf = gsel ? gH : gX;
#pragma unroll
      for (int r = 0; r < 16; ++r) {
        int bl = (r & 3) + ((r >> 2) << 3) + ((lane >> 5) << 2);
        gbuf[(mtile * 32 + bl) * 36 + brow] = tot[r];
      }
      __syncthreads();

      u64* hw64 = (u64*)(hSelf + (size_t)(rs + 1) * HB);
      const bool last = (s == (layer ? SEQ : SEQ - 1));
#pragma unroll
      for (int it = 0; it < 2; ++it) {
        int item = tid + it * 256;
        int b = item >> 3, j = item & 7;
        float vi = gX[b * 36 + j] + gH[b * 36 + j] + bls[j];
        float vf = gX[b * 36 + 8 + j] + gH[b * 36 + 8 + j] + bls[8 + j];
        float vg = gX[b * 36 + 16 + j] + gH[b * 36 + 16 + j] + bls[16 + j];
        float vo = gX[b * 36 + 24 + j] + gH[b * 36 + 24 + j] + bls[24 + j];
        float i_ = sigf(vi), f_ = sigf(vf), g_ = tanhfast(vg), o_ = sigf(vo);
        float cp = cst[item];
        float hn = o_ * tanhfast(cp);  // faithful: h uses PREVIOUS cell state
        float cn = f_ * cp + i_ * g_;
        cst[item] = cn;
        int col = j0 + j;
        // pack 4 cols into u64, one WT store per 4 lanes
        union { _Float16 h; unsigned short u; } hb; hb.h = (_Float16)hn;
        unsigned lo = (unsigned)hb.u;
        unsigned pr1 = (unsigned)__shfl_xor((int)lo, 1, 64);
        unsigned pk32 = lo | (pr1 << 16);
        u64 pr2 = (u64)(unsigned)__shfl_xor((int)pk32, 2, 64);
        if ((j & 3) == 0) {
          u64 v = (u64)pk32 | (pr2 << 32);
          __hip_atomic_store(hw64 + b * 256 + (col >> 2), v, __ATOMIC_RELAXED,
                             __HIP_MEMORY_SCOPE_AGENT);
        }
        if (layer) __builtin_nontemporal_store(hn, &outy[(size_t)t * HB + b * HID + col]);
        if (last) {
          __builtin_nontemporal_store(hn, &outh[layer * HB + b * HID + col]);
          __builtin_nontemporal_store(cn, &outc[layer * HB + b * HID + col]);
        }
      }
    }
    if (s == SEQ) break;

    // ---- release: per-wave drain + LDS arrive; last wave publishes WG flag ----
    asm volatile("s_waitcnt vmcnt(0)" ::: "memory");
    if (lane == 0) {
      unsigned old = atomicAdd(arrCnt, 1u);
      if (old == 4u * (unsigned)s + 3u) {
        unsigned fv = layer ? (unsigned)s : (unsigned)(s + 1);
        __hip_atomic_store(&flags[wg], fv, __ATOMIC_RELAXED, __HIP_MEMORY_SCOPE_AGENT);
      }
    }

    // ---- hierarchical epoch barrier (wave 0 only) ----
    if (wave == 0) {
      if (wg == 0) {
        // leader0: sweep layer0 flags until min >= s+1, publish E0 to 4 mirrors
        const u64* f64 = (const u64*)flags;
        const unsigned target = (unsigned)(s + 1);
        bool ok;
        do {
          u64 a = __hip_atomic_load(f64 + lane, __ATOMIC_RELAXED, __HIP_MEMORY_SCOPE_AGENT);
          unsigned t1 = (unsigned)a, t2 = (unsigned)(a >> 32);
          unsigned mn = t1 < t2 ? t1 : t2;
          ok = __all(mn >= target);
          if (!ok) __builtin_amdgcn_s_sleep(1);
        } while (!ok);
        if (lane < 4)
          __hip_atomic_store(&epoch[lane * 16], target, __ATOMIC_RELAXED,
                             __HIP_MEMORY_SCOPE_AGENT);
      } else if (wg == 128) {
        // leader1: sweep layer1 flags until min >= s, publish E1; then wait E0 >= s+1
        const u64* f64 = (const u64*)flags;
        const unsigned target1 = (unsigned)s;
        bool ok;
        do {
          u64 a = __hip_atomic_load(f64 + 64 + lane, __ATOMIC_RELAXED, __HIP_MEMORY_SCOPE_AGENT);
          unsigned t1 = (unsigned)a, t2 = (unsigned)(a >> 32);
          unsigned mn = t1 < t2 ? t1 : t2;
          ok = __all(mn >= target1);
          if (!ok) __builtin_amdgcn_s_sleep(1);
        } while (!ok);
        if (lane < 4)
          __hip_atomic_store(&epoch[lane * 16 + 1], target1, __ATOMIC_RELAXED,
                             __HIP_MEMORY_SCOPE_AGENT);
        const unsigned target0 = (unsigned)(s + 1);
        for (;;) {
          unsigned e0 = __hip_atomic_load(&epoch[0], __ATOMIC_RELAXED, __HIP_MEMORY_SCOPE_AGENT);
          if (e0 >= target0) break;
          __builtin_amdgcn_s_sleep(1);
        }
      } else {
        // member: poll single 8B epoch word on mirror line
        const u64* em = ((const u64*)epoch) + (size_t)(wg & 3) * 8;
        const unsigned tgt0 = (unsigned)(s + 1);
        const unsigned tgt1 = (unsigned)s;
        int fast = 6;
        for (;;) {
          u64 e = __hip_atomic_load(em, __ATOMIC_RELAXED, __HIP_MEMORY_SCOPE_AGENT);
          unsigned e0 = (unsigned)e, e1 = (unsigned)(e >> 32);
          if (e0 >= tgt0 && (!layer || e1 >= tgt1)) break;
          if (fast-- > 0) __builtin_amdgcn_s_sleep(1);
          else __builtin_amdgcn_s_sleep(8);
        }
      }
    }
    __syncthreads();
  }
}

extern "C" void kernel_launch(void* const* d_in, const int* in_sizes, int n_in,
                              void* d_out, int out_size, void* d_ws, size_t ws_size,
                              hipStream_t stream) {
  const float* x = (const float*)d_in[0];
  const float* Wih0 = (const float*)d_in[1];
  const float* Whh0 = (const float*)d_in[2];
  const float* b0 = (const float*)d_in[3];
  const float* Wih1 = (const float*)d_in[4];
  const float* Whh1 = (const float*)d_in[5];
  const float* b1 = (const float*)d_in[6];
  float* out = (float*)d_out;

  char* ws = (char*)d_ws;
  _Float16* xh = (_Float16*)ws;                    // 512*64*1024 f16 = 67,108,864 B
  _Float16* h0 = (_Float16*)(ws + 67108864);       // 513 slices x 131072 B
  _Float16* h1 = (_Float16*)(ws + 134348800);      // 513 slices x 131072 B
  unsigned* flags = (unsigned*)(ws + 201588736);   // 256 u32 (layer0: 0..127, layer1: 128..255)
  unsigned* epoch = (unsigned*)(ws + 201589760);   // 4 mirror lines x 64 B: {E0,E1}

  hipMemsetAsync(h0, 0, 131072, stream);
  hipMemsetAsync(h1, 0, 131072, stream);
  hipMemsetAsync(flags, 0, 2048, stream);  // flags + epoch mirrors
  cvt_f32_f16<<<2048, 256, 0, stream>>>(x, xh, 33554432 / 4);
  lstm_fused<<<256, 256, LDS_TOTAL, stream>>>(xh, Wih0, Whh0, b0, Wih1, Whh1, b1,
                                              h0, h1, flags, epoch, out);
}